// Round 2
// baseline (316.132 us; speedup 1.0000x reference)
//
#include <hip/hip_runtime.h>

#define B_ 8
#define T_ 4096
#define E_ 1024
#define K_ 128

typedef __bf16 bf16;
typedef bf16 bf16x8 __attribute__((ext_vector_type(8)));
typedef bf16 bf16x4 __attribute__((ext_vector_type(4)));
typedef float f32x4 __attribute__((ext_vector_type(4)));

// ---------------- K0: convert mu to bf16 ----------------
__global__ __launch_bounds__(256) void k0_cvt_mu(const float* __restrict__ mu,
                                                 bf16* __restrict__ mub) {
    int i = blockIdx.x * 256 + threadIdx.x;
    mub[i] = (bf16)mu[i];
}

// ---------------- K1: attP[h,b,k,t] = sum_{e in half h} mu[k,e]*x[b,t,e] (raw, unscaled) ----
// grid (T/64, 2, B), 256 thr (4 waves). Wave: 16 t-cols x 128 k-rows, e-half inner loop.
__global__ __launch_bounds__(256) void k1_att(const float* __restrict__ x,
                                              const bf16* __restrict__ mub,
                                              float* __restrict__ attP) {
    const int b = blockIdx.z;
    const int h = blockIdx.y;
    const int wave = threadIdx.x >> 6;
    const int lane = threadIdx.x & 63;
    const int g = lane >> 4;
    const int ln = lane & 15;
    const int t = blockIdx.x * 64 + wave * 16 + ln;

    f32x4 acc[8];
#pragma unroll
    for (int m = 0; m < 8; ++m) acc[m] = (f32x4){0.f, 0.f, 0.f, 0.f};

    const float* xrow = x + ((size_t)b * T_ + t) * E_ + h * 512;
    const bf16* mu0 = mub + h * 512;
#pragma unroll 1
    for (int e0 = 0; e0 < 512; e0 += 32) {
        const int e = e0 + g * 8;
        f32x4 u0 = *(const f32x4*)(xrow + e);
        f32x4 u1 = *(const f32x4*)(xrow + e + 4);
        bf16x8 bf;
        bf[0] = (bf16)u0[0]; bf[1] = (bf16)u0[1]; bf[2] = (bf16)u0[2]; bf[3] = (bf16)u0[3];
        bf[4] = (bf16)u1[0]; bf[5] = (bf16)u1[1]; bf[6] = (bf16)u1[2]; bf[7] = (bf16)u1[3];
#pragma unroll
        for (int m = 0; m < 8; ++m) {
            bf16x8 af = *(const bf16x8*)(mu0 + (size_t)(m * 16 + ln) * E_ + e);
            acc[m] = __builtin_amdgcn_mfma_f32_16x16x32_bf16(af, bf, acc[m], 0, 0, 0);
        }
    }
#pragma unroll
    for (int m = 0; m < 8; ++m) {
#pragma unroll
        for (int r = 0; r < 4; ++r) {
            const int krow = m * 16 + g * 4 + r;
            attP[(((size_t)h * B_ + b) * K_ + krow) * T_ + t] = acc[m][r];
        }
    }
}

// ---------------- K2: fused half-sum + softmax -> attp bf16 ----------------
// grid (B*K rows), 256 thr. Each thread owns 16 t-values (4 x f32x4, stride 256).
__global__ __launch_bounds__(256) void k2_softmax(const float* __restrict__ attP,
                                                  bf16* __restrict__ attp) {
    const int row = blockIdx.x;   // b*K + k
    const int tid = threadIdx.x;
    const f32x4* p0 = (const f32x4*)(attP + (size_t)row * T_);
    const f32x4* p1 = (const f32x4*)(attP + ((size_t)(B_ * K_) + row) * T_);
    f32x4 v[4];
    float m = -1e30f;
#pragma unroll
    for (int i = 0; i < 4; ++i) {
        f32x4 a = p0[i * 256 + tid];
        f32x4 c = p1[i * 256 + tid];
        v[i] = (a + c) * 0.03125f;
        m = fmaxf(m, fmaxf(fmaxf(v[i][0], v[i][1]), fmaxf(v[i][2], v[i][3])));
    }
#pragma unroll
    for (int off = 32; off > 0; off >>= 1) m = fmaxf(m, __shfl_xor(m, off));
    __shared__ float redm[4], reds[4];
    const int wave = tid >> 6, lane = tid & 63;
    if (lane == 0) redm[wave] = m;
    __syncthreads();
    m = fmaxf(fmaxf(redm[0], redm[1]), fmaxf(redm[2], redm[3]));
    float s = 0.f;
#pragma unroll
    for (int i = 0; i < 4; ++i) {
        v[i][0] = __expf(v[i][0] - m);
        v[i][1] = __expf(v[i][1] - m);
        v[i][2] = __expf(v[i][2] - m);
        v[i][3] = __expf(v[i][3] - m);
        s += v[i][0] + v[i][1] + v[i][2] + v[i][3];
    }
#pragma unroll
    for (int off = 32; off > 0; off >>= 1) s += __shfl_xor(s, off);
    if (lane == 0) reds[wave] = s;
    __syncthreads();
    const float inv = 1.f / (reds[0] + reds[1] + reds[2] + reds[3]);
    bf16x4* outp = (bf16x4*)(attp + (size_t)row * T_);
#pragma unroll
    for (int i = 0; i < 4; ++i) {
        bf16x4 o;
        o[0] = (bf16)(v[i][0] * inv);
        o[1] = (bf16)(v[i][1] * inv);
        o[2] = (bf16)(v[i][2] * inv);
        o[3] = (bf16)(v[i][3] * inv);
        outp[i * 256 + tid] = o;
    }
}

// ---------------- K3: attpT[b,t,k] = attp[b,k,t] (bf16 transpose) ----------------
// grid (T/64, B), 256 thr. Tile [128 k][64 t] via LDS.
__global__ __launch_bounds__(256) void k3_transpose(const bf16* __restrict__ attp,
                                                    bf16* __restrict__ attpT) {
    const int b = blockIdx.y;
    const int t0 = blockIdx.x * 64;
    const int tid = threadIdx.x;
    __shared__ bf16 tile[128][72];
#pragma unroll
    for (int p = 0; p < 4; ++p) {
        const int kk = p * 32 + (tid >> 3);
        const int tl = (tid & 7) * 8;
        bf16x8 vv = *(const bf16x8*)(attp + ((size_t)b * K_ + kk) * T_ + t0 + tl);
        *(bf16x8*)&tile[kk][tl] = vv;
    }
    __syncthreads();
    const int tt = tid >> 2;
    const int ks = (tid & 3) * 32;
#pragma unroll
    for (int q = 0; q < 4; ++q) {
        bf16x8 o;
#pragma unroll
        for (int j = 0; j < 8; ++j) o[j] = tile[ks + q * 8 + j][tt];
        *(bf16x8*)(attpT + ((size_t)b * T_ + t0 + tt) * K_ + ks + q * 8) = o;
    }
}

// ---------------- K4: selp[c,b,k,e] = sum_{t in chunk c} attp[b,k,t]*x[b,t,e] ----------------
// grid (E/64, 8 chunks, B), 256 thr (4 waves). Wave: 16 e-cols x 128 k-rows.
__global__ __launch_bounds__(256) void k4_sel(const float* __restrict__ x,
                                              const bf16* __restrict__ attp,
                                              float* __restrict__ selp) {
    const int eblk = blockIdx.x;
    const int chunk = blockIdx.y;
    const int b = blockIdx.z;
    const int wave = threadIdx.x >> 6;
    const int lane = threadIdx.x & 63;
    const int g = lane >> 4, ln = lane & 15;
    const int e = eblk * 64 + wave * 16 + ln;

    f32x4 acc[8];
#pragma unroll
    for (int m = 0; m < 8; ++m) acc[m] = (f32x4){0.f, 0.f, 0.f, 0.f};

    const int tbase = chunk * 512;
#pragma unroll 1
    for (int t0 = 0; t0 < 512; t0 += 32) {
        const int t = tbase + t0 + g * 8;
        bf16x8 bf;
#pragma unroll
        for (int j = 0; j < 8; ++j)
            bf[j] = (bf16)x[((size_t)b * T_ + t + j) * E_ + e];
#pragma unroll
        for (int m = 0; m < 8; ++m) {
            bf16x8 af = *(const bf16x8*)(attp + ((size_t)b * K_ + m * 16 + ln) * T_ + t);
            acc[m] = __builtin_amdgcn_mfma_f32_16x16x32_bf16(af, bf, acc[m], 0, 0, 0);
        }
    }
#pragma unroll
    for (int m = 0; m < 8; ++m) {
#pragma unroll
        for (int r = 0; r < 4; ++r) {
            const int krow = m * 16 + g * 4 + r;
            selp[(((size_t)chunk * B_ + b) * K_ + krow) * E_ + e] = acc[m][r];
        }
    }
}

// ---------------- K4b: reduce 8 chunks + write sel transposed bf16 [b][e][k] ----------------
__global__ __launch_bounds__(256) void k4b_reduce_t(const float* __restrict__ selp,
                                                    bf16* __restrict__ selbT) {
    const int gid = blockIdx.x * 256 + threadIdx.x;  // B*E*K = 1M
    const int kk = gid & 127;
    const int e = (gid >> 7) & 1023;
    const int b = gid >> 17;
    float s = 0.f;
#pragma unroll
    for (int c = 0; c < 8; ++c)
        s += selp[(((size_t)c * B_ + b) * K_ + kk) * E_ + e];
    selbT[((size_t)b * E_ + e) * K_ + kk] = (bf16)s;
}

// ---------------- K5: out = k*(x + attp^T @ sel) + b ----------------
// grid (T/128, E/128, B), 256 thr (4 waves). Wave: 128 t x 32 e.
__global__ __launch_bounds__(256) void k5_out(const float* __restrict__ x,
                                              const bf16* __restrict__ attpT,
                                              const bf16* __restrict__ selbT,
                                              const float* __restrict__ kp,
                                              const float* __restrict__ bp,
                                              float* __restrict__ out) {
    const int b = blockIdx.z;
    const int t0 = blockIdx.x * 128;
    const int wave = threadIdx.x >> 6;
    const int lane = threadIdx.x & 63;
    const int g = lane >> 4, ln = lane & 15;
    const int e0 = blockIdx.y * 128 + wave * 32;
    const float kk = kp[0], bb = bp[0];

    f32x4 acc[8][2];
#pragma unroll
    for (int m = 0; m < 8; ++m) {
        acc[m][0] = (f32x4){0.f, 0.f, 0.f, 0.f};
        acc[m][1] = (f32x4){0.f, 0.f, 0.f, 0.f};
    }

#pragma unroll
    for (int ks = 0; ks < 4; ++ks) {
        const int k0 = ks * 32 + g * 8;
        bf16x8 bf0 = *(const bf16x8*)(selbT + ((size_t)b * E_ + e0 + ln) * K_ + k0);
        bf16x8 bf1 = *(const bf16x8*)(selbT + ((size_t)b * E_ + e0 + 16 + ln) * K_ + k0);
#pragma unroll
        for (int m = 0; m < 8; ++m) {
            bf16x8 af = *(const bf16x8*)(attpT + ((size_t)b * T_ + t0 + m * 16 + ln) * K_ + k0);
            acc[m][0] = __builtin_amdgcn_mfma_f32_16x16x32_bf16(af, bf0, acc[m][0], 0, 0, 0);
            acc[m][1] = __builtin_amdgcn_mfma_f32_16x16x32_bf16(af, bf1, acc[m][1], 0, 0, 0);
        }
    }

#pragma unroll
    for (int m = 0; m < 8; ++m) {
#pragma unroll
        for (int nt = 0; nt < 2; ++nt) {
#pragma unroll
            for (int r = 0; r < 4; ++r) {
                const int t = t0 + m * 16 + g * 4 + r;
                const int e = e0 + nt * 16 + ln;
                const size_t idx = ((size_t)b * T_ + t) * E_ + e;
                out[idx] = kk * (x[idx] + acc[m][nt][r]) + bb;
            }
        }
    }
}

extern "C" void kernel_launch(void* const* d_in, const int* in_sizes, int n_in,
                              void* d_out, int out_size, void* d_ws, size_t ws_size,
                              hipStream_t stream) {
    const float* x  = (const float*)d_in[0];
    const float* mu = (const float*)d_in[1];
    // d_in[2]=bias, d_in[3]=Wr, d_in[4]=Wl are dead code in the reference forward.
    const float* kp = (const float*)d_in[5];
    const float* bp = (const float*)d_in[6];
    float* out = (float*)d_out;

    char* ws = (char*)d_ws;
    // Region A (33,554,432 B): attP (K1 writes, K2 reads) then reused as selp
    // (K4 writes, K4b reads) — stream-ordered, no overlap hazard.
    float* attP  = (float*)(ws);
    float* selp  = (float*)(ws);
    bf16*  attp  = (bf16*)(ws + 33554432);   // 8,388,608
    bf16*  attpT = (bf16*)(ws + 41943040);   // 8,388,608
    bf16*  selbT = (bf16*)(ws + 50331648);   // 2,097,152
    bf16*  mub   = (bf16*)(ws + 52428800);   //   262,144   (total 52,690,944 B)

    k0_cvt_mu<<<dim3(512), 256, 0, stream>>>(mu, mub);
    k1_att<<<dim3(64, 2, 8), 256, 0, stream>>>(x, mub, attP);
    k2_softmax<<<dim3(1024), 256, 0, stream>>>(attP, attp);
    k3_transpose<<<dim3(64, 8), 256, 0, stream>>>(attp, attpT);
    k4_sel<<<dim3(16, 8, 8), 256, 0, stream>>>(x, attp, selp);
    k4b_reduce_t<<<dim3(4096), 256, 0, stream>>>(selp, selbT);
    k5_out<<<dim3(32, 8, 8), 256, 0, stream>>>(x, attpT, selbT, kp, bp, out);
}

// Round 3
// 311.460 us; speedup vs baseline: 1.0150x; 1.0150x over previous
//
#include <hip/hip_runtime.h>

#define B_ 8
#define T_ 4096
#define E_ 1024
#define K_ 128

typedef __bf16 bf16;
typedef bf16 bf16x8 __attribute__((ext_vector_type(8)));
typedef bf16 bf16x4 __attribute__((ext_vector_type(4)));
typedef float f32x4 __attribute__((ext_vector_type(4)));

// ---------------- K0: convert mu to bf16 ----------------
__global__ __launch_bounds__(256) void k0_cvt_mu(const float* __restrict__ mu,
                                                 bf16* __restrict__ mub) {
    int i = blockIdx.x * 256 + threadIdx.x;
    mub[i] = (bf16)mu[i];
}

// ---------------- K0x: xbT[b,e,t] = (bf16)x[b,t,e] (transpose-convert) ----------------
// grid (T/64, E/64, B), 256 thr. LDS tile [64t][70e-padded].
__global__ __launch_bounds__(256) void k0x_transpose(const float* __restrict__ x,
                                                     bf16* __restrict__ xbT) {
    const int b = blockIdx.z;
    const int t0 = blockIdx.x * 64;
    const int e0 = blockIdx.y * 64;
    const int tid = threadIdx.x;
    __shared__ bf16 tile[64][70];
    const int tr = tid >> 4;       // 0..15
    const int es = tid & 15;       // e-slot (4 floats)
#pragma unroll
    for (int r = 0; r < 4; ++r) {
        const int t = r * 16 + tr;
        f32x4 v = *(const f32x4*)(x + ((size_t)(b * T_ + t0 + t)) * E_ + e0 + es * 4);
        bf16x4 o;
        o[0] = (bf16)v[0]; o[1] = (bf16)v[1]; o[2] = (bf16)v[2]; o[3] = (bf16)v[3];
        // two 4B writes (b64 would be misaligned for odd rows with pad 70)
        *(bf16*)&tile[t][es * 4 + 0] = o[0];
        *(bf16*)&tile[t][es * 4 + 1] = o[1];
        *(bf16*)&tile[t][es * 4 + 2] = o[2];
        *(bf16*)&tile[t][es * 4 + 3] = o[3];
    }
    __syncthreads();
    const int e = tid >> 2;        // 0..63
    const int ts = tid & 3;
#pragma unroll
    for (int q = 0; q < 2; ++q) {
        const int tt = (ts + q * 4) * 8;   // 0..56 step 8
        bf16x8 o;
#pragma unroll
        for (int j = 0; j < 8; ++j) o[j] = tile[tt + j][e];
        *(bf16x8*)(xbT + ((size_t)b * E_ + e0 + e) * T_ + t0 + tt) = o;
    }
}

// ---------------- K1: att[b,k,t] = (1/32) * sum_e mu[k,e] * x[b,t,e] ----------------
// grid (T/64, B), 256 thr (4 waves). Wave handles 16 t-cols x all 128 k-rows.
__global__ __launch_bounds__(256) void k1_att(const float* __restrict__ x,
                                              const bf16* __restrict__ mub,
                                              float* __restrict__ att) {
    const int b = blockIdx.y;
    const int wave = threadIdx.x >> 6;
    const int lane = threadIdx.x & 63;
    const int g = lane >> 4;
    const int ln = lane & 15;
    const int t = blockIdx.x * 64 + wave * 16 + ln;

    f32x4 acc[8];
#pragma unroll
    for (int m = 0; m < 8; ++m) acc[m] = (f32x4){0.f, 0.f, 0.f, 0.f};

    const float* xrow = x + ((size_t)b * T_ + t) * E_;
#pragma unroll 1
    for (int e0 = 0; e0 < E_; e0 += 32) {
        const int e = e0 + g * 8;
        f32x4 u0 = *(const f32x4*)(xrow + e);
        f32x4 u1 = *(const f32x4*)(xrow + e + 4);
        bf16x8 bf;
        bf[0] = (bf16)u0[0]; bf[1] = (bf16)u0[1]; bf[2] = (bf16)u0[2]; bf[3] = (bf16)u0[3];
        bf[4] = (bf16)u1[0]; bf[5] = (bf16)u1[1]; bf[6] = (bf16)u1[2]; bf[7] = (bf16)u1[3];
#pragma unroll
        for (int m = 0; m < 8; ++m) {
            bf16x8 af = *(const bf16x8*)(mub + (size_t)(m * 16 + ln) * E_ + e);
            acc[m] = __builtin_amdgcn_mfma_f32_16x16x32_bf16(af, bf, acc[m], 0, 0, 0);
        }
    }
#pragma unroll
    for (int m = 0; m < 8; ++m) {
#pragma unroll
        for (int r = 0; r < 4; ++r) {
            const int krow = m * 16 + g * 4 + r;
            att[((size_t)b * K_ + krow) * T_ + t] = acc[m][r] * 0.03125f;
        }
    }
}

// ---------------- K2: fused softmax -> attp bf16 ----------------
__global__ __launch_bounds__(256) void k2_softmax(const float* __restrict__ att,
                                                  bf16* __restrict__ attp) {
    const int row = blockIdx.x;   // b*K + k
    const int tid = threadIdx.x;
    const f32x4* p = (const f32x4*)(att + (size_t)row * T_);
    f32x4 v[4];
    float m = -1e30f;
#pragma unroll
    for (int i = 0; i < 4; ++i) {
        v[i] = p[i * 256 + tid];
        m = fmaxf(m, fmaxf(fmaxf(v[i][0], v[i][1]), fmaxf(v[i][2], v[i][3])));
    }
#pragma unroll
    for (int off = 32; off > 0; off >>= 1) m = fmaxf(m, __shfl_xor(m, off));
    __shared__ float redm[4], reds[4];
    const int wave = tid >> 6, lane = tid & 63;
    if (lane == 0) redm[wave] = m;
    __syncthreads();
    m = fmaxf(fmaxf(redm[0], redm[1]), fmaxf(redm[2], redm[3]));
    float s = 0.f;
#pragma unroll
    for (int i = 0; i < 4; ++i) {
        v[i][0] = __expf(v[i][0] - m);
        v[i][1] = __expf(v[i][1] - m);
        v[i][2] = __expf(v[i][2] - m);
        v[i][3] = __expf(v[i][3] - m);
        s += v[i][0] + v[i][1] + v[i][2] + v[i][3];
    }
#pragma unroll
    for (int off = 32; off > 0; off >>= 1) s += __shfl_xor(s, off);
    if (lane == 0) reds[wave] = s;
    __syncthreads();
    const float inv = 1.f / (reds[0] + reds[1] + reds[2] + reds[3]);
    bf16x4* outp = (bf16x4*)(attp + (size_t)row * T_);
#pragma unroll
    for (int i = 0; i < 4; ++i) {
        bf16x4 o;
        o[0] = (bf16)(v[i][0] * inv);
        o[1] = (bf16)(v[i][1] * inv);
        o[2] = (bf16)(v[i][2] * inv);
        o[3] = (bf16)(v[i][3] * inv);
        outp[i * 256 + tid] = o;
    }
}

// ---------------- K3: attpT[b,t,k] = attp[b,k,t] (bf16 transpose) ----------------
__global__ __launch_bounds__(256) void k3_transpose(const bf16* __restrict__ attp,
                                                    bf16* __restrict__ attpT) {
    const int b = blockIdx.y;
    const int t0 = blockIdx.x * 64;
    const int tid = threadIdx.x;
    __shared__ bf16 tile[128][72];
#pragma unroll
    for (int p = 0; p < 4; ++p) {
        const int kk = p * 32 + (tid >> 3);
        const int tl = (tid & 7) * 8;
        bf16x8 vv = *(const bf16x8*)(attp + ((size_t)b * K_ + kk) * T_ + t0 + tl);
        *(bf16x8*)&tile[kk][tl] = vv;
    }
    __syncthreads();
    const int tt = tid >> 2;
    const int ks = (tid & 3) * 32;
#pragma unroll
    for (int q = 0; q < 4; ++q) {
        bf16x8 o;
#pragma unroll
        for (int j = 0; j < 8; ++j) o[j] = tile[ks + q * 8 + j][tt];
        *(bf16x8*)(attpT + ((size_t)b * T_ + t0 + tt) * K_ + ks + q * 8) = o;
    }
}

// ---------------- K4: selp[c,b,k,e] = sum_{t in chunk c} attp[b,k,t]*xbT[b,e,t] ----------------
// grid (E/64, 4 chunks, B), 256 thr (4 waves). Wave: 16 e-cols x 128 k-rows.
__global__ __launch_bounds__(256) void k4_sel(const bf16* __restrict__ xbT,
                                              const bf16* __restrict__ attp,
                                              float* __restrict__ selp) {
    const int eblk = blockIdx.x;
    const int chunk = blockIdx.y;
    const int b = blockIdx.z;
    const int wave = threadIdx.x >> 6;
    const int lane = threadIdx.x & 63;
    const int g = lane >> 4, ln = lane & 15;
    const int e = eblk * 64 + wave * 16 + ln;

    f32x4 acc[8];
#pragma unroll
    for (int m = 0; m < 8; ++m) acc[m] = (f32x4){0.f, 0.f, 0.f, 0.f};

    const bf16* xcol = xbT + ((size_t)b * E_ + e) * T_;
    const int tbase = chunk * 1024;
#pragma unroll 1
    for (int t0 = 0; t0 < 1024; t0 += 32) {
        const int t = tbase + t0 + g * 8;
        bf16x8 bf = *(const bf16x8*)(xcol + t);
#pragma unroll
        for (int m = 0; m < 8; ++m) {
            bf16x8 af = *(const bf16x8*)(attp + ((size_t)b * K_ + m * 16 + ln) * T_ + t);
            acc[m] = __builtin_amdgcn_mfma_f32_16x16x32_bf16(af, bf, acc[m], 0, 0, 0);
        }
    }
#pragma unroll
    for (int m = 0; m < 8; ++m) {
#pragma unroll
        for (int r = 0; r < 4; ++r) {
            const int krow = m * 16 + g * 4 + r;
            selp[(((size_t)chunk * B_ + b) * K_ + krow) * E_ + e] = acc[m][r];
        }
    }
}

// ---------------- K4b: coalesced reduce over chunks + transpose -> selbT[b,e,k] bf16 ----------------
// grid (E/64, B), 256 thr. LDS tile [128k][70e-padded].
__global__ __launch_bounds__(256) void k4b_reduce_t(const float* __restrict__ selp,
                                                    bf16* __restrict__ selbT) {
    const int ec = blockIdx.x;
    const int b = blockIdx.y;
    const int tid = threadIdx.x;
    const int e0 = ec * 64;
    __shared__ bf16 tl[128][70];
    // phase 1: 128 k-rows x 16 f32x4 slots = 2048 slots, 8 rounds; e fastest -> coalesced
#pragma unroll
    for (int r = 0; r < 8; ++r) {
        const int slot = r * 256 + tid;
        const int k = slot >> 4;
        const int es = slot & 15;
        f32x4 s = (f32x4){0.f, 0.f, 0.f, 0.f};
#pragma unroll
        for (int c = 0; c < 4; ++c)
            s += *(const f32x4*)(selp + (((size_t)c * B_ + b) * K_ + k) * E_ + e0 + es * 4);
        tl[k][es * 4 + 0] = (bf16)s[0];
        tl[k][es * 4 + 1] = (bf16)s[1];
        tl[k][es * 4 + 2] = (bf16)s[2];
        tl[k][es * 4 + 3] = (bf16)s[3];
    }
    __syncthreads();
    // phase 2: 64 e-rows x 16 bf16x8 k-slots = 1024 slots, 4 rounds; contiguous stores
#pragma unroll
    for (int r = 0; r < 4; ++r) {
        const int slot = r * 256 + tid;
        const int e = slot >> 4;
        const int ks = slot & 15;
        bf16x8 o;
#pragma unroll
        for (int j = 0; j < 8; ++j) o[j] = tl[ks * 8 + j][e];
        *(bf16x8*)(selbT + ((size_t)b * E_ + e0 + e) * K_ + ks * 8) = o;
    }
}

// ---------------- K5: out = k*(x + attp^T @ sel) + b ----------------
// grid (T/128, E/128, B), 256 thr (4 waves). Wave: 128 t x 32 e.
__global__ __launch_bounds__(256) void k5_out(const float* __restrict__ x,
                                              const bf16* __restrict__ attpT,
                                              const bf16* __restrict__ selbT,
                                              const float* __restrict__ kp,
                                              const float* __restrict__ bp,
                                              float* __restrict__ out) {
    const int b = blockIdx.z;
    const int t0 = blockIdx.x * 128;
    const int wave = threadIdx.x >> 6;
    const int lane = threadIdx.x & 63;
    const int g = lane >> 4, ln = lane & 15;
    const int e0 = blockIdx.y * 128 + wave * 32;
    const float kk = kp[0], bb = bp[0];

    f32x4 acc[8][2];
#pragma unroll
    for (int m = 0; m < 8; ++m) {
        acc[m][0] = (f32x4){0.f, 0.f, 0.f, 0.f};
        acc[m][1] = (f32x4){0.f, 0.f, 0.f, 0.f};
    }

#pragma unroll
    for (int ks = 0; ks < 4; ++ks) {
        const int k0 = ks * 32 + g * 8;
        bf16x8 bf0 = *(const bf16x8*)(selbT + ((size_t)b * E_ + e0 + ln) * K_ + k0);
        bf16x8 bf1 = *(const bf16x8*)(selbT + ((size_t)b * E_ + e0 + 16 + ln) * K_ + k0);
#pragma unroll
        for (int m = 0; m < 8; ++m) {
            bf16x8 af = *(const bf16x8*)(attpT + ((size_t)b * T_ + t0 + m * 16 + ln) * K_ + k0);
            acc[m][0] = __builtin_amdgcn_mfma_f32_16x16x32_bf16(af, bf0, acc[m][0], 0, 0, 0);
            acc[m][1] = __builtin_amdgcn_mfma_f32_16x16x32_bf16(af, bf1, acc[m][1], 0, 0, 0);
        }
    }

#pragma unroll
    for (int m = 0; m < 8; ++m) {
#pragma unroll
        for (int nt = 0; nt < 2; ++nt) {
#pragma unroll
            for (int r = 0; r < 4; ++r) {
                const int t = t0 + m * 16 + g * 4 + r;
                const int e = e0 + nt * 16 + ln;
                const size_t idx = ((size_t)b * T_ + t) * E_ + e;
                out[idx] = kk * (x[idx] + acc[m][nt][r]) + bb;
            }
        }
    }
}

extern "C" void kernel_launch(void* const* d_in, const int* in_sizes, int n_in,
                              void* d_out, int out_size, void* d_ws, size_t ws_size,
                              hipStream_t stream) {
    const float* x  = (const float*)d_in[0];
    const float* mu = (const float*)d_in[1];
    // d_in[2]=bias, d_in[3]=Wr, d_in[4]=Wl are dead code in the reference forward.
    const float* kp = (const float*)d_in[5];
    const float* bp = (const float*)d_in[6];
    float* out = (float*)d_out;

    char* ws = (char*)d_ws;
    float* att   = (float*)(ws);             // 16,777,216
    bf16*  attp  = (bf16*)(ws + 16777216);   //  8,388,608
    bf16*  attpT = (bf16*)(ws + 25165824);   //  8,388,608
    float* selp  = (float*)(ws + 33554432);  // 16,777,216
    bf16*  selbT = (bf16*)(ws + 50331648);   //  2,097,152
    bf16*  mub   = (bf16*)(ws + 52428800);   //    262,144  (total 52,690,944 B)
    // xbT (67 MB bf16 [B][E][T]) lives in d_out scratch space: written by K0x,
    // read by K4, fully overwritten by K5's final output. Stream-ordered, safe.
    bf16*  xbT   = (bf16*)d_out;

    k0_cvt_mu<<<dim3(512), 256, 0, stream>>>(mu, mub);
    k0x_transpose<<<dim3(64, 16, 8), 256, 0, stream>>>(x, xbT);
    k1_att<<<dim3(64, 8), 256, 0, stream>>>(x, mub, att);
    k2_softmax<<<dim3(1024), 256, 0, stream>>>(att, attp);
    k3_transpose<<<dim3(64, 8), 256, 0, stream>>>(attp, attpT);
    k4_sel<<<dim3(16, 4, 8), 256, 0, stream>>>(xbT, attp, selp);
    k4b_reduce_t<<<dim3(16, 8), 256, 0, stream>>>(selp, selbT);
    k5_out<<<dim3(32, 8, 8), 256, 0, stream>>>(x, attpT, selbT, kp, bp, out);
}

// Round 4
// 311.250 us; speedup vs baseline: 1.0157x; 1.0007x over previous
//
#include <hip/hip_runtime.h>

#define B_ 8
#define T_ 4096
#define E_ 1024
#define K_ 128

typedef __bf16 bf16;
typedef bf16 bf16x8 __attribute__((ext_vector_type(8)));
typedef bf16 bf16x4 __attribute__((ext_vector_type(4)));
typedef float f32x4 __attribute__((ext_vector_type(4)));

// ---------------- K0: convert mu to bf16 ----------------
__global__ __launch_bounds__(256) void k0_cvt_mu(const float* __restrict__ mu,
                                                 bf16* __restrict__ mub) {
    int i = blockIdx.x * 256 + threadIdx.x;
    mub[i] = (bf16)mu[i];
}

// ---------------- K0x: xb[b,t,e] = (bf16)x ; xbT[b,e,t] = (bf16)x transposed ----------------
// grid (T/64, E/64, B), 256 thr. LDS tile [64t][70e-padded].
__global__ __launch_bounds__(256) void k0x_cvt(const float* __restrict__ x,
                                               bf16* __restrict__ xb,
                                               bf16* __restrict__ xbT) {
    const int b = blockIdx.z;
    const int t0 = blockIdx.x * 64;
    const int e0 = blockIdx.y * 64;
    const int tid = threadIdx.x;
    __shared__ bf16 tile[64][70];
    const int tr = tid >> 4;       // 0..15
    const int es = tid & 15;       // e-slot (4 floats)
#pragma unroll
    for (int r = 0; r < 4; ++r) {
        const int t = r * 16 + tr;
        f32x4 v = *(const f32x4*)(x + ((size_t)(b * T_ + t0 + t)) * E_ + e0 + es * 4);
        bf16x4 o;
        o[0] = (bf16)v[0]; o[1] = (bf16)v[1]; o[2] = (bf16)v[2]; o[3] = (bf16)v[3];
        *(bf16x4*)(xb + ((size_t)(b * T_ + t0 + t)) * E_ + e0 + es * 4) = o;
        tile[t][es * 4 + 0] = o[0];
        tile[t][es * 4 + 1] = o[1];
        tile[t][es * 4 + 2] = o[2];
        tile[t][es * 4 + 3] = o[3];
    }
    __syncthreads();
    const int e = tid >> 2;        // 0..63
    const int ts = tid & 3;
#pragma unroll
    for (int q = 0; q < 2; ++q) {
        const int tt = (ts + q * 4) * 8;
        bf16x8 o;
#pragma unroll
        for (int j = 0; j < 8; ++j) o[j] = tile[tt + j][e];
        *(bf16x8*)(xbT + ((size_t)b * E_ + e0 + e) * T_ + t0 + tt) = o;
    }
}

// ---------------- K1: attP[h,b,k,t] = sum_{e in half h} mu[k,e]*xb[b,t,e] ----------------
// grid (T/64, 2, B), 256 thr (4 waves). Wave: 16 t x 128 k. 4096 waves = 4/SIMD.
__global__ __launch_bounds__(256) void k1_att(const bf16* __restrict__ xb,
                                              const bf16* __restrict__ mub,
                                              float* __restrict__ attP) {
    const int b = blockIdx.z;
    const int h = blockIdx.y;
    const int wave = threadIdx.x >> 6;
    const int lane = threadIdx.x & 63;
    const int g = lane >> 4;
    const int ln = lane & 15;
    const int t = blockIdx.x * 64 + wave * 16 + ln;

    f32x4 acc[8];
#pragma unroll
    for (int m = 0; m < 8; ++m) acc[m] = (f32x4){0.f, 0.f, 0.f, 0.f};

    const bf16* xrow = xb + ((size_t)b * T_ + t) * E_ + h * 512 + g * 8;
    const bf16* mu0 = mub + h * 512 + g * 8;
#pragma unroll 2
    for (int e0 = 0; e0 < 512; e0 += 32) {
        bf16x8 bf = *(const bf16x8*)(xrow + e0);
#pragma unroll
        for (int m = 0; m < 8; ++m) {
            bf16x8 af = *(const bf16x8*)(mu0 + (size_t)(m * 16 + ln) * E_ + e0);
            acc[m] = __builtin_amdgcn_mfma_f32_16x16x32_bf16(af, bf, acc[m], 0, 0, 0);
        }
    }
#pragma unroll
    for (int m = 0; m < 8; ++m) {
#pragma unroll
        for (int r = 0; r < 4; ++r) {
            const int krow = m * 16 + g * 4 + r;
            attP[(((size_t)h * B_ + b) * K_ + krow) * T_ + t] = acc[m][r];
        }
    }
}

// ---------------- K2: fused half-sum + softmax -> attp bf16 ----------------
__global__ __launch_bounds__(256) void k2_softmax(const float* __restrict__ attP,
                                                  bf16* __restrict__ attp) {
    const int row = blockIdx.x;   // b*K + k
    const int tid = threadIdx.x;
    const f32x4* p0 = (const f32x4*)(attP + (size_t)row * T_);
    const f32x4* p1 = (const f32x4*)(attP + ((size_t)(B_ * K_) + row) * T_);
    f32x4 v[4];
    float m = -1e30f;
#pragma unroll
    for (int i = 0; i < 4; ++i) {
        f32x4 a = p0[i * 256 + tid];
        f32x4 c = p1[i * 256 + tid];
        v[i] = (a + c) * 0.03125f;
        m = fmaxf(m, fmaxf(fmaxf(v[i][0], v[i][1]), fmaxf(v[i][2], v[i][3])));
    }
#pragma unroll
    for (int off = 32; off > 0; off >>= 1) m = fmaxf(m, __shfl_xor(m, off));
    __shared__ float redm[4], reds[4];
    const int wave = tid >> 6, lane = tid & 63;
    if (lane == 0) redm[wave] = m;
    __syncthreads();
    m = fmaxf(fmaxf(redm[0], redm[1]), fmaxf(redm[2], redm[3]));
    float s = 0.f;
#pragma unroll
    for (int i = 0; i < 4; ++i) {
        v[i][0] = __expf(v[i][0] - m);
        v[i][1] = __expf(v[i][1] - m);
        v[i][2] = __expf(v[i][2] - m);
        v[i][3] = __expf(v[i][3] - m);
        s += v[i][0] + v[i][1] + v[i][2] + v[i][3];
    }
#pragma unroll
    for (int off = 32; off > 0; off >>= 1) s += __shfl_xor(s, off);
    if (lane == 0) reds[wave] = s;
    __syncthreads();
    const float inv = 1.f / (reds[0] + reds[1] + reds[2] + reds[3]);
    bf16x4* outp = (bf16x4*)(attp + (size_t)row * T_);
#pragma unroll
    for (int i = 0; i < 4; ++i) {
        bf16x4 o;
        o[0] = (bf16)(v[i][0] * inv);
        o[1] = (bf16)(v[i][1] * inv);
        o[2] = (bf16)(v[i][2] * inv);
        o[3] = (bf16)(v[i][3] * inv);
        outp[i * 256 + tid] = o;
    }
}

// ---------------- K3: attpT[b,t,k] = attp[b,k,t] ----------------
__global__ __launch_bounds__(256) void k3_transpose(const bf16* __restrict__ attp,
                                                    bf16* __restrict__ attpT) {
    const int b = blockIdx.y;
    const int t0 = blockIdx.x * 64;
    const int tid = threadIdx.x;
    __shared__ bf16 tile[128][72];
#pragma unroll
    for (int p = 0; p < 4; ++p) {
        const int kk = p * 32 + (tid >> 3);
        const int tl = (tid & 7) * 8;
        bf16x8 vv = *(const bf16x8*)(attp + ((size_t)b * K_ + kk) * T_ + t0 + tl);
        *(bf16x8*)&tile[kk][tl] = vv;
    }
    __syncthreads();
    const int tt = tid >> 2;
    const int ks = (tid & 3) * 32;
#pragma unroll
    for (int q = 0; q < 4; ++q) {
        bf16x8 o;
#pragma unroll
        for (int j = 0; j < 8; ++j) o[j] = tile[ks + q * 8 + j][tt];
        *(bf16x8*)(attpT + ((size_t)b * T_ + t0 + tt) * K_ + ks + q * 8) = o;
    }
}

// ---------------- K4: selpT[c,b,e,k] = sum_{t in chunk c} attp[b,k,t]*xbT[b,e,t] ----------------
// grid (E/64, 8 chunks, B), 256 thr (4 waves). 4096 waves = 4/SIMD.
// Epilogue: LDS transpose so stores are k-fastest, fully coalesced.
__global__ __launch_bounds__(256) void k4_sel(const bf16* __restrict__ xbT,
                                              const bf16* __restrict__ attp,
                                              float* __restrict__ selpT) {
    const int eblk = blockIdx.x;
    const int chunk = blockIdx.y;
    const int b = blockIdx.z;
    const int tid = threadIdx.x;
    const int wave = tid >> 6;
    const int lane = tid & 63;
    const int g = lane >> 4, ln = lane & 15;
    const int e0 = eblk * 64;
    const int e = e0 + wave * 16 + ln;

    f32x4 acc[8];
#pragma unroll
    for (int m = 0; m < 8; ++m) acc[m] = (f32x4){0.f, 0.f, 0.f, 0.f};

    const bf16* xcol = xbT + ((size_t)b * E_ + e) * T_ + chunk * 512 + g * 8;
    const bf16* arow = attp + (size_t)b * K_ * T_ + chunk * 512 + g * 8;
#pragma unroll 2
    for (int t0 = 0; t0 < 512; t0 += 32) {
        bf16x8 bf = *(const bf16x8*)(xcol + t0);
#pragma unroll
        for (int m = 0; m < 8; ++m) {
            bf16x8 af = *(const bf16x8*)(arow + (size_t)(m * 16 + ln) * T_ + t0);
            acc[m] = __builtin_amdgcn_mfma_f32_16x16x32_bf16(af, bf, acc[m], 0, 0, 0);
        }
    }
    __shared__ float tl[64][132];
#pragma unroll
    for (int m = 0; m < 8; ++m)
#pragma unroll
        for (int r = 0; r < 4; ++r)
            tl[wave * 16 + ln][m * 16 + g * 4 + r] = acc[m][r];
    __syncthreads();
    float* dst = selpT + ((size_t)chunk * B_ + b) * E_ * K_ + (size_t)e0 * K_;
#pragma unroll
    for (int rr = 0; rr < 8; ++rr) {
        const int slot = rr * 256 + tid;
        const int ee = slot >> 5;
        const int kq = slot & 31;
        *(f32x4*)(dst + (size_t)ee * K_ + kq * 4) = *(f32x4*)&tl[ee][kq * 4];
    }
}

// ---------------- K4b: flat reduce over 8 chunks -> selbT bf16 [b][e][k] ----------------
__global__ __launch_bounds__(256) void k4b_reduce(const float* __restrict__ selpT,
                                                  bf16* __restrict__ selbT) {
    const size_t gid = (size_t)blockIdx.x * 256 + threadIdx.x;  // 262144 f32x4 slots
    const size_t f = gid * 4;
    f32x4 s = (f32x4){0.f, 0.f, 0.f, 0.f};
#pragma unroll
    for (int c = 0; c < 8; ++c)
        s += *(const f32x4*)(selpT + (size_t)c * (B_ * E_ * K_) + f);
    bf16x4 o;
    o[0] = (bf16)s[0]; o[1] = (bf16)s[1]; o[2] = (bf16)s[2]; o[3] = (bf16)s[3];
    *(bf16x4*)(selbT + f) = o;
}

// ---------------- K5: out = k*(xb + attpT @ selbT) + b ----------------
// grid (T/128, E/64, B), 256 thr (4 waves). Wave: 128 t x 16 e. 16384 waves.
__global__ __launch_bounds__(256) void k5_out(const bf16* __restrict__ xb,
                                              const bf16* __restrict__ attpT,
                                              const bf16* __restrict__ selbT,
                                              const float* __restrict__ kp,
                                              const float* __restrict__ bp,
                                              float* __restrict__ out) {
    const int b = blockIdx.z;
    const int t0 = blockIdx.x * 128;
    const int wave = threadIdx.x >> 6;
    const int lane = threadIdx.x & 63;
    const int g = lane >> 4, ln = lane & 15;
    const int e = blockIdx.y * 64 + wave * 16 + ln;
    const float kk = kp[0], bb = bp[0];

    f32x4 acc[8];
#pragma unroll
    for (int m = 0; m < 8; ++m) acc[m] = (f32x4){0.f, 0.f, 0.f, 0.f};

    const bf16* brow = selbT + ((size_t)b * E_ + e) * K_ + g * 8;
    const bf16* arow = attpT + ((size_t)b * T_ + t0 + ln) * K_ + g * 8;
#pragma unroll
    for (int ks = 0; ks < 4; ++ks) {
        bf16x8 bf = *(const bf16x8*)(brow + ks * 32);
#pragma unroll
        for (int m = 0; m < 8; ++m) {
            bf16x8 af = *(const bf16x8*)(arow + (size_t)(m * 16) * K_ + ks * 32);
            acc[m] = __builtin_amdgcn_mfma_f32_16x16x32_bf16(af, bf, acc[m], 0, 0, 0);
        }
    }
#pragma unroll
    for (int m = 0; m < 8; ++m) {
#pragma unroll
        for (int r = 0; r < 4; ++r) {
            const int t = t0 + m * 16 + g * 4 + r;
            const size_t idx = ((size_t)b * T_ + t) * E_ + e;
            out[idx] = kk * ((float)xb[idx] + acc[m][r]) + bb;
        }
    }
}

extern "C" void kernel_launch(void* const* d_in, const int* in_sizes, int n_in,
                              void* d_out, int out_size, void* d_ws, size_t ws_size,
                              hipStream_t stream) {
    const float* x  = (const float*)d_in[0];
    const float* mu = (const float*)d_in[1];
    // d_in[2]=bias, d_in[3]=Wr, d_in[4]=Wl are dead code in the reference forward.
    const float* kp = (const float*)d_in[5];
    const float* bp = (const float*)d_in[6];
    float* out = (float*)d_out;

    char* ws = (char*)d_ws;
    bf16*  xb    = (bf16*)(ws);                       //  67,108,864
    bf16*  xbT   = (bf16*)(ws + 67108864);            //  67,108,864
    float* attP  = (float*)(ws + 134217728);          //  33,554,432
    bf16*  attp  = (bf16*)(ws + 167772160);           //   8,388,608
    bf16*  attpT = (bf16*)(ws + 176160768);           //   8,388,608
    float* selpT = (float*)(ws + 184549376);          //  33,554,432
    bf16*  selbT = (bf16*)(ws + 218103808);           //   2,097,152
    bf16*  mub   = (bf16*)(ws + 220200960);           //     262,144  (~210 MB total)

    k0_cvt_mu<<<dim3(512), 256, 0, stream>>>(mu, mub);
    k0x_cvt<<<dim3(64, 16, 8), 256, 0, stream>>>(x, xb, xbT);
    k1_att<<<dim3(64, 2, 8), 256, 0, stream>>>(xb, mub, attP);
    k2_softmax<<<dim3(1024), 256, 0, stream>>>(attP, attp);
    k3_transpose<<<dim3(64, 8), 256, 0, stream>>>(attp, attpT);
    k4_sel<<<dim3(16, 8, 8), 256, 0, stream>>>(xbT, attp, selpT);
    k4b_reduce<<<dim3(1024), 256, 0, stream>>>(selpT, selbT);
    k5_out<<<dim3(32, 16, 8), 256, 0, stream>>>(xb, attpT, selbT, kp, bp, out);
}